// Round 7
// baseline (89.135 us; speedup 1.0000x reference)
//
#include <hip/hip_runtime.h>
#include <stdint.h>

#define G_SHOWERS 8192
#define NBINS (2 * G_SHOWERS)  // bin = kind*8192 + sid; kind: 0=hits, 1=tracks

typedef float f32x4 __attribute__((ext_vector_type(4)));

// ws layout (nb slabs, slab region reused by both element passes):
//   [0, nb*64K)   : partial slabs u32/f32 [nb][NBINS]
//   [+0,   +64K)  : bmax_g u32[NBINS]
//   [+64K, +128K) : corr_g u32[NBINS]   (zeroed by bmax_kernel block 0)
//   [+128K,+384K) : table  f32[G][8]
//   [+384K, ...)  : binbuf u16[n] (optional, if ws large enough)

// ---- K1: per-block beta-max partials in LDS + bin stash; blk0 zeroes corr_g
__global__ __launch_bounds__(1024) void bmax_kernel(
    const int* __restrict__ sid, const int* __restrict__ hitid,
    const float* __restrict__ beta, unsigned* __restrict__ partial,
    unsigned* __restrict__ corr_g, unsigned short* __restrict__ binbuf, int n) {
    __shared__ unsigned bm[NBINS];
    {
        uint4 z = {0u, 0u, 0u, 0u};
        uint4* bm4 = reinterpret_cast<uint4*>(bm);
        for (int i = threadIdx.x; i < NBINS / 4; i += 1024) bm4[i] = z;
        if (blockIdx.x == 0) {
            uint4* cg4 = reinterpret_cast<uint4*>(corr_g);
            for (int i = threadIdx.x; i < NBINS / 4; i += 1024) cg4[i] = z;
        }
    }
    __syncthreads();

    const int tid = blockIdx.x * blockDim.x + threadIdx.x;
    const int stride = gridDim.x * blockDim.x;
    const int nv = n >> 2;
    const int nvh = nv >> 1;  // pairs: group i and group i+nvh

    for (int i = tid; i < nvh; i += stride) {
        int4   s4a = reinterpret_cast<const int4*>(sid)[i];
        int4   s4b = reinterpret_cast<const int4*>(sid)[i + nvh];
        int4   h4a = reinterpret_cast<const int4*>(hitid)[i];
        int4   h4b = reinterpret_cast<const int4*>(hitid)[i + nvh];
        float4 b4a = reinterpret_cast<const float4*>(beta)[i];
        float4 b4b = reinterpret_cast<const float4*>(beta)[i + nvh];

        const int* sp = (const int*)&s4a;
        const int* hp = (const int*)&h4a;
        const float* bp = (const float*)&b4a;
        ushort4 bva;
        unsigned short* bvp = (unsigned short*)&bva;
        #pragma unroll
        for (int j = 0; j < 4; ++j) {
            int bin = (hp[j] != 0 ? G_SHOWERS : 0) + sp[j];
            bvp[j] = (unsigned short)bin;
            atomicMax(&bm[bin], __float_as_uint(bp[j]));
        }
        sp = (const int*)&s4b;
        hp = (const int*)&h4b;
        bp = (const float*)&b4b;
        ushort4 bvb;
        bvp = (unsigned short*)&bvb;
        #pragma unroll
        for (int j = 0; j < 4; ++j) {
            int bin = (hp[j] != 0 ? G_SHOWERS : 0) + sp[j];
            bvp[j] = (unsigned short)bin;
            atomicMax(&bm[bin], __float_as_uint(bp[j]));
        }
        if (binbuf) {
            reinterpret_cast<ushort4*>(binbuf)[i]       = bva;
            reinterpret_cast<ushort4*>(binbuf)[i + nvh] = bvb;
        }
    }
    // residue: odd middle group (if nv odd) + scalar tail
    const int tail_start = 4 * (2 * nvh);
    for (int i = tail_start + tid; i < n; i += stride) {
        int bin = (hitid[i] != 0 ? G_SHOWERS : 0) + sid[i];
        if (binbuf) binbuf[i] = (unsigned short)bin;
        atomicMax(&bm[bin], __float_as_uint(beta[i]));
    }

    __syncthreads();
    {
        uint4* outp = reinterpret_cast<uint4*>(partial + (size_t)blockIdx.x * NBINS);
        const uint4* bm4 = reinterpret_cast<const uint4*>(bm);
        for (int i = threadIdx.x; i < NBINS / 4; i += 1024) outp[i] = bm4[i];
    }
}

// ---- R1: reduce bmax partials, 4 quarter-chains per bin, coalesced ---------
__global__ __launch_bounds__(256) void bmax_reduce(
    const unsigned* __restrict__ partial, unsigned* __restrict__ bmax_g, int nb) {
    const int q = threadIdx.x >> 6, lane = threadIdx.x & 63;
    const int bin = blockIdx.x * 64 + lane;
    unsigned m = 0u;
    #pragma unroll 8
    for (int b = q; b < nb; b += 4)
        m = max(m, partial[(size_t)b * NBINS + bin]);
    __shared__ unsigned red[4][64];
    red[q][lane] = m;
    __syncthreads();
    if (q == 0)
        bmax_g[bin] = max(max(red[0][lane], red[1][lane]),
                          max(red[2][lane], red[3][lane]));
}

// ---- K3: esum partials in LDS + sparse corr atomicMax ----------------------
__global__ __launch_bounds__(1024) void esum_corr_kernel(
    const int* __restrict__ sid, const int* __restrict__ hitid,
    const float* __restrict__ energy, const float* __restrict__ beta,
    const float* __restrict__ corr, const unsigned* __restrict__ bmax_g,
    float* __restrict__ partial_e, unsigned* __restrict__ corr_g,
    const unsigned short* __restrict__ binbuf, int n) {
    __shared__ float es[NBINS];
    {
        f32x4 z = {0.f, 0.f, 0.f, 0.f};
        f32x4* es4 = reinterpret_cast<f32x4*>(es);
        for (int i = threadIdx.x; i < NBINS / 4; i += 1024) es4[i] = z;
    }
    __syncthreads();

    const int tid = blockIdx.x * blockDim.x + threadIdx.x;
    const int stride = gridDim.x * blockDim.x;
    const int nv = n >> 2;
    const int nvh = nv >> 1;

    for (int i = tid; i < nvh; i += stride) {
        float4 e4a = reinterpret_cast<const float4*>(energy)[i];
        float4 e4b = reinterpret_cast<const float4*>(energy)[i + nvh];
        float4 b4a = reinterpret_cast<const float4*>(beta)[i];
        float4 b4b = reinterpret_cast<const float4*>(beta)[i + nvh];
        float4 c4a = reinterpret_cast<const float4*>(corr)[i];
        float4 c4b = reinterpret_cast<const float4*>(corr)[i + nvh];
        int bins[8];
        if (binbuf) {
            ushort4 bva = reinterpret_cast<const ushort4*>(binbuf)[i];
            ushort4 bvb = reinterpret_cast<const ushort4*>(binbuf)[i + nvh];
            bins[0] = bva.x; bins[1] = bva.y; bins[2] = bva.z; bins[3] = bva.w;
            bins[4] = bvb.x; bins[5] = bvb.y; bins[6] = bvb.z; bins[7] = bvb.w;
        } else {
            int4 s4a = reinterpret_cast<const int4*>(sid)[i];
            int4 s4b = reinterpret_cast<const int4*>(sid)[i + nvh];
            int4 h4a = reinterpret_cast<const int4*>(hitid)[i];
            int4 h4b = reinterpret_cast<const int4*>(hitid)[i + nvh];
            const int* sp = (const int*)&s4a;
            const int* hp = (const int*)&h4a;
            #pragma unroll
            for (int j = 0; j < 4; ++j)
                bins[j] = (hp[j] != 0 ? G_SHOWERS : 0) + sp[j];
            sp = (const int*)&s4b;
            hp = (const int*)&h4b;
            #pragma unroll
            for (int j = 0; j < 4; ++j)
                bins[4 + j] = (hp[j] != 0 ? G_SHOWERS : 0) + sp[j];
        }
        const float* ep = (const float*)&e4a;
        const float* bp = (const float*)&b4a;
        const float* cp = (const float*)&c4a;
        #pragma unroll
        for (int j = 0; j < 4; ++j) {
            atomicAdd(&es[bins[j]], ep[j]);
            if (__float_as_uint(bp[j]) == __ldg(&bmax_g[bins[j]]))
                atomicMax(&corr_g[bins[j]], __float_as_uint(cp[j]));  // sparse
        }
        ep = (const float*)&e4b;
        bp = (const float*)&b4b;
        cp = (const float*)&c4b;
        #pragma unroll
        for (int j = 0; j < 4; ++j) {
            atomicAdd(&es[bins[4 + j]], ep[j]);
            if (__float_as_uint(bp[j]) == __ldg(&bmax_g[bins[4 + j]]))
                atomicMax(&corr_g[bins[4 + j]], __float_as_uint(cp[j]));
        }
    }
    const int tail_start = 4 * (2 * nvh);
    for (int i = tail_start + tid; i < n; i += stride) {
        int bin = (hitid[i] != 0 ? G_SHOWERS : 0) + sid[i];
        atomicAdd(&es[bin], energy[i]);
        if (__float_as_uint(beta[i]) == __ldg(&bmax_g[bin]))
            atomicMax(&corr_g[bin], __float_as_uint(corr[i]));
    }

    __syncthreads();
    {
        f32x4* outp = reinterpret_cast<f32x4*>(partial_e + (size_t)blockIdx.x * NBINS);
        const f32x4* es4 = reinterpret_cast<const f32x4*>(es);
        for (int i = threadIdx.x; i < NBINS / 4; i += 1024) outp[i] = es4[i];
    }
}

// ---- T: reduce esum partials (4 chains/shower, coalesced) + build table ----
__global__ __launch_bounds__(256) void table_kernel(
    const float* __restrict__ partial_e, const unsigned* __restrict__ corr_g,
    float* __restrict__ table, int nb) {
    const int q = threadIdx.x >> 6, lane = threadIdx.x & 63;
    const int g = blockIdx.x * 64 + lane;
    float ah = 0.0f, at = 0.0f;
    #pragma unroll 8
    for (int b = q; b < nb; b += 4) {
        const float* p = partial_e + (size_t)b * NBINS;
        ah += p[g];
        at += p[G_SHOWERS + g];
    }
    __shared__ float rh[4][64], rt[4][64];
    rh[q][lane] = ah;
    rt[q][lane] = at;
    __syncthreads();
    if (q == 0) {
        float raw_hit = rh[0][lane] + rh[1][lane] + rh[2][lane] + rh[3][lane];
        float raw_trk = rt[0][lane] + rt[1][lane] + rt[2][lane] + rt[3][lane];
        float cor_hit = __uint_as_float(corr_g[g]) * raw_hit;
        float cor_trk = __uint_as_float(corr_g[G_SHOWERS + g]) * raw_trk;
        float4 lo, hi;
        lo.x = raw_trk; lo.y = cor_trk; lo.z = raw_hit; lo.w = cor_hit;
        hi.x = (raw_trk != 0.0f) ? raw_trk : raw_hit;
        hi.y = (cor_trk != 0.0f) ? cor_trk : cor_hit;
        hi.z = (raw_hit != 0.0f) ? raw_hit : raw_trk;
        hi.w = (cor_hit != 0.0f) ? cor_hit : cor_trk;
        reinterpret_cast<float4*>(table)[2 * g]     = lo;
        reinterpret_cast<float4*>(table)[2 * g + 1] = hi;
    }
}

// ---- G: broadcast gather to 8 output planes (nontemporal stores) -----------
__global__ __launch_bounds__(256) void gather_kernel(
    const int* __restrict__ sid, const unsigned short* __restrict__ binbuf,
    const float* __restrict__ table, float* __restrict__ out, int n) {
    const int tid = blockIdx.x * blockDim.x + threadIdx.x;
    const int stride = gridDim.x * blockDim.x;
    const int nv = n >> 2;
    const f32x4* tbl = reinterpret_cast<const f32x4*>(table);

    for (int i = tid; i < nv; i += stride) {
        int s0, s1, s2, s3;
        if (binbuf) {
            ushort4 bv = reinterpret_cast<const ushort4*>(binbuf)[i];
            s0 = bv.x & (G_SHOWERS - 1); s1 = bv.y & (G_SHOWERS - 1);
            s2 = bv.z & (G_SHOWERS - 1); s3 = bv.w & (G_SHOWERS - 1);
        } else {
            int4 s4 = reinterpret_cast<const int4*>(sid)[i];
            s0 = s4.x; s1 = s4.y; s2 = s4.z; s3 = s4.w;
        }
        f32x4 ax = tbl[2 * s0], bx = tbl[2 * s0 + 1];
        f32x4 ay = tbl[2 * s1], by = tbl[2 * s1 + 1];
        f32x4 az = tbl[2 * s2], bz = tbl[2 * s2 + 1];
        f32x4 aw = tbl[2 * s3], bw = tbl[2 * s3 + 1];

        f32x4 p;
        p.x = ax.x; p.y = ay.x; p.z = az.x; p.w = aw.x;
        __builtin_nontemporal_store(p, reinterpret_cast<f32x4*>(out + 0ll * n) + i);
        p.x = ax.y; p.y = ay.y; p.z = az.y; p.w = aw.y;
        __builtin_nontemporal_store(p, reinterpret_cast<f32x4*>(out + 1ll * n) + i);
        p.x = ax.z; p.y = ay.z; p.z = az.z; p.w = aw.z;
        __builtin_nontemporal_store(p, reinterpret_cast<f32x4*>(out + 2ll * n) + i);
        p.x = ax.w; p.y = ay.w; p.z = az.w; p.w = aw.w;
        __builtin_nontemporal_store(p, reinterpret_cast<f32x4*>(out + 3ll * n) + i);
        p.x = bx.x; p.y = by.x; p.z = bz.x; p.w = bw.x;
        __builtin_nontemporal_store(p, reinterpret_cast<f32x4*>(out + 4ll * n) + i);
        p.x = bx.y; p.y = by.y; p.z = bz.y; p.w = bw.y;
        __builtin_nontemporal_store(p, reinterpret_cast<f32x4*>(out + 5ll * n) + i);
        p.x = bx.z; p.y = by.z; p.z = bz.z; p.w = bw.z;
        __builtin_nontemporal_store(p, reinterpret_cast<f32x4*>(out + 6ll * n) + i);
        p.x = bx.w; p.y = by.w; p.z = bz.w; p.w = bw.w;
        __builtin_nontemporal_store(p, reinterpret_cast<f32x4*>(out + 7ll * n) + i);
    }
    for (int i = nv * 4 + tid; i < n; i += stride) {
        int s = sid[i];
        #pragma unroll
        for (int k = 0; k < 8; ++k)
            out[(long long)k * n + i] = table[8 * s + k];
    }
}

extern "C" void kernel_launch(void* const* d_in, const int* in_sizes, int n_in,
                              void* d_out, int out_size, void* d_ws, size_t ws_size,
                              hipStream_t stream) {
    const int*   sid    = (const int*)d_in[0];
    const int*   hitid  = (const int*)d_in[1];
    const float* energy = (const float*)d_in[2];
    const float* beta   = (const float*)d_in[3];
    const float* corr   = (const float*)d_in[4];
    const int n = in_sizes[0];

    const size_t slab_bytes = (size_t)NBINS * 4;  // 64 KB
    const size_t fixed_bytes = 6 * slab_bytes;    // bmax_g + corr_g + table
    int nb = 256;
    if (ws_size < (size_t)nb * slab_bytes + fixed_bytes) {
        size_t avail = (ws_size > fixed_bytes) ? (ws_size - fixed_bytes) : slab_bytes;
        nb = (int)(avail / slab_bytes) & ~3;
        if (nb < 8) nb = 8;
        if (nb > 256) nb = 256;
    }

    char* base = (char*)d_ws;
    unsigned* partial = (unsigned*)base;   // slab region reused by both passes
    unsigned* bmax_g  = (unsigned*)(base + (size_t)nb * slab_bytes);
    unsigned* corr_g  = (unsigned*)((char*)bmax_g + slab_bytes);
    float*    table   = (float*)((char*)corr_g + slab_bytes);

    size_t used = (size_t)nb * slab_bytes + fixed_bytes;
    size_t bin_bytes = ((size_t)n * 2 + 255) & ~(size_t)255;
    unsigned short* binbuf = nullptr;
    if (ws_size >= used + bin_bytes)
        binbuf = (unsigned short*)(base + used);

    bmax_kernel<<<nb, 1024, 0, stream>>>(sid, hitid, beta, partial, corr_g,
                                         binbuf, n);
    bmax_reduce<<<NBINS / 64, 256, 0, stream>>>(partial, bmax_g, nb);
    esum_corr_kernel<<<nb, 1024, 0, stream>>>(sid, hitid, energy, beta, corr,
                                              bmax_g, (float*)partial, corr_g,
                                              binbuf, n);
    table_kernel<<<G_SHOWERS / 64, 256, 0, stream>>>((float*)partial, corr_g,
                                                     table, nb);
    gather_kernel<<<2048, 256, 0, stream>>>(sid, binbuf, table, (float*)d_out, n);
}

// Round 8
// 88.688 us; speedup vs baseline: 1.0050x; 1.0050x over previous
//
#include <hip/hip_runtime.h>
#include <stdint.h>

#define G_SHOWERS 8192
#define NBINS (2 * G_SHOWERS)  // bin = kind*8192 + sid; kind: 0=hits, 1=tracks

typedef float f32x4 __attribute__((ext_vector_type(4)));

// ws layout (nb slabs, slab region reused by both element passes):
//   [0, nb*64K)   : partial slabs u32/f32 [nb][NBINS]
//   [+0,   +64K)  : bmax_g u32[NBINS]
//   [+64K, +128K) : corr_g u32[NBINS]   (zeroed by bmax_kernel block 0)
//   [+128K,+384K) : table  f32[G][8]
//   [+384K, ...)  : binbuf u16[n] (optional, if ws large enough)

// ---- K1: per-block beta-max partials in LDS + bin stash; blk0 zeroes corr_g
__global__ __launch_bounds__(1024) void bmax_kernel(
    const int* __restrict__ sid, const int* __restrict__ hitid,
    const float* __restrict__ beta, unsigned* __restrict__ partial,
    unsigned* __restrict__ corr_g, unsigned short* __restrict__ binbuf, int n) {
    __shared__ unsigned bm[NBINS];
    for (int i = threadIdx.x; i < NBINS; i += 1024) bm[i] = 0u;
    if (blockIdx.x == 0)
        for (int i = threadIdx.x; i < NBINS; i += 1024) corr_g[i] = 0u;
    __syncthreads();

    const int tid = blockIdx.x * blockDim.x + threadIdx.x;
    const int stride = gridDim.x * blockDim.x;
    const int nv = n >> 2;
    for (int i = tid; i < nv; i += stride) {
        int4   s4 = reinterpret_cast<const int4*>(sid)[i];
        int4   h4 = reinterpret_cast<const int4*>(hitid)[i];
        float4 b4 = reinterpret_cast<const float4*>(beta)[i];
        const int* sp = (const int*)&s4;
        const int* hp = (const int*)&h4;
        const float* bp = (const float*)&b4;
        ushort4 bv;
        unsigned short* bvp = (unsigned short*)&bv;
        #pragma unroll
        for (int j = 0; j < 4; ++j) {
            int bin = (hp[j] != 0 ? G_SHOWERS : 0) + sp[j];
            bvp[j] = (unsigned short)bin;
            atomicMax(&bm[bin], __float_as_uint(bp[j]));
        }
        if (binbuf) reinterpret_cast<ushort4*>(binbuf)[i] = bv;
    }
    for (int i = nv * 4 + tid; i < n; i += stride) {
        int bin = (hitid[i] != 0 ? G_SHOWERS : 0) + sid[i];
        if (binbuf) binbuf[i] = (unsigned short)bin;
        atomicMax(&bm[bin], __float_as_uint(beta[i]));
    }

    __syncthreads();
    unsigned* outp = partial + (size_t)blockIdx.x * NBINS;
    for (int i = threadIdx.x; i < NBINS; i += 1024) outp[i] = bm[i];
}

// ---- R1: reduce bmax partials, 4 quarter-chains per bin, coalesced ---------
__global__ __launch_bounds__(256) void bmax_reduce(
    const unsigned* __restrict__ partial, unsigned* __restrict__ bmax_g, int nb) {
    const int q = threadIdx.x >> 6, lane = threadIdx.x & 63;
    const int bin = blockIdx.x * 64 + lane;
    unsigned m = 0u;
    #pragma unroll 8
    for (int b = q; b < nb; b += 4)
        m = max(m, partial[(size_t)b * NBINS + bin]);
    __shared__ unsigned red[4][64];
    red[q][lane] = m;
    __syncthreads();
    if (q == 0)
        bmax_g[bin] = max(max(red[0][lane], red[1][lane]),
                          max(red[2][lane], red[3][lane]));
}

// ---- K3: esum partials in LDS + sparse corr atomicMax ----------------------
__global__ __launch_bounds__(1024) void esum_corr_kernel(
    const int* __restrict__ sid, const int* __restrict__ hitid,
    const float* __restrict__ energy, const float* __restrict__ beta,
    const float* __restrict__ corr, const unsigned* __restrict__ bmax_g,
    float* __restrict__ partial_e, unsigned* __restrict__ corr_g,
    const unsigned short* __restrict__ binbuf, int n) {
    __shared__ float es[NBINS];
    for (int i = threadIdx.x; i < NBINS; i += 1024) es[i] = 0.0f;
    __syncthreads();

    const int tid = blockIdx.x * blockDim.x + threadIdx.x;
    const int stride = gridDim.x * blockDim.x;
    const int nv = n >> 2;
    for (int i = tid; i < nv; i += stride) {
        float4 e4 = reinterpret_cast<const float4*>(energy)[i];
        float4 b4 = reinterpret_cast<const float4*>(beta)[i];
        float4 c4 = reinterpret_cast<const float4*>(corr)[i];
        const float* ep = (const float*)&e4;
        const float* bp = (const float*)&b4;
        const float* cp = (const float*)&c4;
        int bins[4];
        if (binbuf) {
            ushort4 bv = reinterpret_cast<const ushort4*>(binbuf)[i];
            bins[0] = bv.x; bins[1] = bv.y; bins[2] = bv.z; bins[3] = bv.w;
        } else {
            int4 s4 = reinterpret_cast<const int4*>(sid)[i];
            int4 h4 = reinterpret_cast<const int4*>(hitid)[i];
            const int* sp = (const int*)&s4;
            const int* hp = (const int*)&h4;
            #pragma unroll
            for (int j = 0; j < 4; ++j)
                bins[j] = (hp[j] != 0 ? G_SHOWERS : 0) + sp[j];
        }
        #pragma unroll
        for (int j = 0; j < 4; ++j) {
            atomicAdd(&es[bins[j]], ep[j]);
            if (__float_as_uint(bp[j]) == __ldg(&bmax_g[bins[j]]))
                atomicMax(&corr_g[bins[j]], __float_as_uint(cp[j]));  // ~16K total
        }
    }
    for (int i = nv * 4 + tid; i < n; i += stride) {
        int bin = (hitid[i] != 0 ? G_SHOWERS : 0) + sid[i];
        atomicAdd(&es[bin], energy[i]);
        if (__float_as_uint(beta[i]) == __ldg(&bmax_g[bin]))
            atomicMax(&corr_g[bin], __float_as_uint(corr[i]));
    }

    __syncthreads();
    float* outp = partial_e + (size_t)blockIdx.x * NBINS;
    for (int i = threadIdx.x; i < NBINS; i += 1024) outp[i] = es[i];
}

// ---- T: reduce esum partials (4 chains/shower, coalesced) + build table ----
__global__ __launch_bounds__(256) void table_kernel(
    const float* __restrict__ partial_e, const unsigned* __restrict__ corr_g,
    float* __restrict__ table, int nb) {
    const int q = threadIdx.x >> 6, lane = threadIdx.x & 63;
    const int g = blockIdx.x * 64 + lane;
    float ah = 0.0f, at = 0.0f;
    #pragma unroll 8
    for (int b = q; b < nb; b += 4) {
        const float* p = partial_e + (size_t)b * NBINS;
        ah += p[g];
        at += p[G_SHOWERS + g];
    }
    __shared__ float rh[4][64], rt[4][64];
    rh[q][lane] = ah;
    rt[q][lane] = at;
    __syncthreads();
    if (q == 0) {
        float raw_hit = rh[0][lane] + rh[1][lane] + rh[2][lane] + rh[3][lane];
        float raw_trk = rt[0][lane] + rt[1][lane] + rt[2][lane] + rt[3][lane];
        float cor_hit = __uint_as_float(corr_g[g]) * raw_hit;
        float cor_trk = __uint_as_float(corr_g[G_SHOWERS + g]) * raw_trk;
        float4 lo, hi;
        lo.x = raw_trk; lo.y = cor_trk; lo.z = raw_hit; lo.w = cor_hit;
        hi.x = (raw_trk != 0.0f) ? raw_trk : raw_hit;
        hi.y = (cor_trk != 0.0f) ? cor_trk : cor_hit;
        hi.z = (raw_hit != 0.0f) ? raw_hit : raw_trk;
        hi.w = (cor_hit != 0.0f) ? cor_hit : cor_trk;
        reinterpret_cast<float4*>(table)[2 * g]     = lo;
        reinterpret_cast<float4*>(table)[2 * g + 1] = hi;
    }
}

// ---- G: broadcast gather to 8 output planes (nontemporal stores) -----------
__global__ __launch_bounds__(256) void gather_kernel(
    const int* __restrict__ sid, const unsigned short* __restrict__ binbuf,
    const float* __restrict__ table, float* __restrict__ out, int n) {
    const int tid = blockIdx.x * blockDim.x + threadIdx.x;
    const int stride = gridDim.x * blockDim.x;
    const int nv = n >> 2;
    const f32x4* tbl = reinterpret_cast<const f32x4*>(table);

    for (int i = tid; i < nv; i += stride) {
        int s0, s1, s2, s3;
        if (binbuf) {
            ushort4 bv = reinterpret_cast<const ushort4*>(binbuf)[i];
            s0 = bv.x & (G_SHOWERS - 1); s1 = bv.y & (G_SHOWERS - 1);
            s2 = bv.z & (G_SHOWERS - 1); s3 = bv.w & (G_SHOWERS - 1);
        } else {
            int4 s4 = reinterpret_cast<const int4*>(sid)[i];
            s0 = s4.x; s1 = s4.y; s2 = s4.z; s3 = s4.w;
        }
        f32x4 ax = tbl[2 * s0], bx = tbl[2 * s0 + 1];
        f32x4 ay = tbl[2 * s1], by = tbl[2 * s1 + 1];
        f32x4 az = tbl[2 * s2], bz = tbl[2 * s2 + 1];
        f32x4 aw = tbl[2 * s3], bw = tbl[2 * s3 + 1];

        f32x4 p;
        p.x = ax.x; p.y = ay.x; p.z = az.x; p.w = aw.x;
        __builtin_nontemporal_store(p, reinterpret_cast<f32x4*>(out + 0ll * n) + i);
        p.x = ax.y; p.y = ay.y; p.z = az.y; p.w = aw.y;
        __builtin_nontemporal_store(p, reinterpret_cast<f32x4*>(out + 1ll * n) + i);
        p.x = ax.z; p.y = ay.z; p.z = az.z; p.w = aw.z;
        __builtin_nontemporal_store(p, reinterpret_cast<f32x4*>(out + 2ll * n) + i);
        p.x = ax.w; p.y = ay.w; p.z = az.w; p.w = aw.w;
        __builtin_nontemporal_store(p, reinterpret_cast<f32x4*>(out + 3ll * n) + i);
        p.x = bx.x; p.y = by.x; p.z = bz.x; p.w = bw.x;
        __builtin_nontemporal_store(p, reinterpret_cast<f32x4*>(out + 4ll * n) + i);
        p.x = bx.y; p.y = by.y; p.z = bz.y; p.w = bw.y;
        __builtin_nontemporal_store(p, reinterpret_cast<f32x4*>(out + 5ll * n) + i);
        p.x = bx.z; p.y = by.z; p.z = bz.z; p.w = bw.z;
        __builtin_nontemporal_store(p, reinterpret_cast<f32x4*>(out + 6ll * n) + i);
        p.x = bx.w; p.y = by.w; p.z = bz.w; p.w = bw.w;
        __builtin_nontemporal_store(p, reinterpret_cast<f32x4*>(out + 7ll * n) + i);
    }
    for (int i = nv * 4 + tid; i < n; i += stride) {
        int s = sid[i];
        #pragma unroll
        for (int k = 0; k < 8; ++k)
            out[(long long)k * n + i] = table[8 * s + k];
    }
}

extern "C" void kernel_launch(void* const* d_in, const int* in_sizes, int n_in,
                              void* d_out, int out_size, void* d_ws, size_t ws_size,
                              hipStream_t stream) {
    const int*   sid    = (const int*)d_in[0];
    const int*   hitid  = (const int*)d_in[1];
    const float* energy = (const float*)d_in[2];
    const float* beta   = (const float*)d_in[3];
    const float* corr   = (const float*)d_in[4];
    const int n = in_sizes[0];

    const size_t slab_bytes = (size_t)NBINS * 4;  // 64 KB
    const size_t fixed_bytes = 6 * slab_bytes;    // bmax_g + corr_g + table
    int nb = 256;
    if (ws_size < (size_t)nb * slab_bytes + fixed_bytes) {
        size_t avail = (ws_size > fixed_bytes) ? (ws_size - fixed_bytes) : slab_bytes;
        nb = (int)(avail / slab_bytes) & ~3;
        if (nb < 8) nb = 8;
        if (nb > 256) nb = 256;
    }

    char* base = (char*)d_ws;
    unsigned* partial = (unsigned*)base;   // slab region reused by both passes
    unsigned* bmax_g  = (unsigned*)(base + (size_t)nb * slab_bytes);
    unsigned* corr_g  = (unsigned*)((char*)bmax_g + slab_bytes);
    float*    table   = (float*)((char*)corr_g + slab_bytes);

    size_t used = (size_t)nb * slab_bytes + fixed_bytes;
    size_t bin_bytes = ((size_t)n * 2 + 255) & ~(size_t)255;
    unsigned short* binbuf = nullptr;
    if (ws_size >= used + bin_bytes)
        binbuf = (unsigned short*)(base + used);

    bmax_kernel<<<nb, 1024, 0, stream>>>(sid, hitid, beta, partial, corr_g,
                                         binbuf, n);
    bmax_reduce<<<NBINS / 64, 256, 0, stream>>>(partial, bmax_g, nb);
    esum_corr_kernel<<<nb, 1024, 0, stream>>>(sid, hitid, energy, beta, corr,
                                              bmax_g, (float*)partial, corr_g,
                                              binbuf, n);
    table_kernel<<<G_SHOWERS / 64, 256, 0, stream>>>((float*)partial, corr_g,
                                                     table, nb);
    gather_kernel<<<2048, 256, 0, stream>>>(sid, binbuf, table, (float*)d_out, n);
}